// Round 5
// baseline (1387.838 us; speedup 1.0000x reference)
//
#include <hip/hip_runtime.h>
#include <hip/hip_bf16.h>
#include <cstdint>
#include <cstddef>

#define VOCAB 50001
#define EMB 64
#define HID 128
#define G4  512   // 4*HID
#define TAGS 32
#define BATCH 256
#define SEQ 512

typedef _Float16 f16;
typedef _Float16 f16x2 __attribute__((ext_vector_type(2)));
typedef _Float16 f16x8 __attribute__((ext_vector_type(8)));
typedef float f32x4 __attribute__((ext_vector_type(4)));

__device__ __forceinline__ f16x2 bc_h2(unsigned int x) {
  return __builtin_bit_cast(f16x2, x);
}

#if __has_builtin(__builtin_amdgcn_fdot2)
__device__ __forceinline__ float FDOT2(f16x2 a, f16x2 b, float c) {
  return __builtin_amdgcn_fdot2(a, b, c, false);
}
#else
__device__ __forceinline__ float FDOT2(f16x2 a, f16x2 b, float c) {
  return c + (float)a.x * (float)b.x + (float)a.y * (float)b.y;
}
#endif

__device__ __forceinline__ float fsig(float x) {
  return 1.0f / (1.0f + __expf(-x));
}
__device__ __forceinline__ float ftanh(float x) {
  float e = __expf(2.0f * x);
  return 1.0f - 2.0f / (e + 1.0f);
}

// ---------------------------------------------------------------------------
// Kernel A: gate tables  G[v, j] = sum_k E[v,k] * Wk[k,j] + b[j]   (f16 out)
// (unchanged from R4 — works, ~50-70us; revisit if it shows in top-5)
// ---------------------------------------------------------------------------
__global__ __launch_bounds__(256)
void gtab_kernel(const float* __restrict__ E,
                 const float* __restrict__ Wk_f, const float* __restrict__ b_f,
                 const float* __restrict__ Wk_b, const float* __restrict__ b_b,
                 f16* __restrict__ G_f, f16* __restrict__ G_b) {
  const int dir = blockIdx.z;
  const float* __restrict__ Wk   = dir ? Wk_b : Wk_f;
  const float* __restrict__ bias = dir ? b_b  : b_f;
  f16* __restrict__ G = dir ? G_b : G_f;

  __shared__ f16x2 Eh[64][33];
  __shared__ f16x2 Wh[64][33];

  const int m0 = blockIdx.x * 64;
  const int n0 = blockIdx.y * 64;
  const int tid = threadIdx.x;

  #pragma unroll
  for (int s = 0; s < 8; ++s) {
    int idx = tid + s * 256;
    int r = idx >> 5, kk = idx & 31;
    int row = m0 + r;
    float2 ev;
    if (row < VOCAB) ev = *(const float2*)(E + (size_t)row * EMB + 2 * kk);
    else { ev.x = 0.f; ev.y = 0.f; }
    f16x2 v; v.x = (f16)ev.x; v.y = (f16)ev.y;
    Eh[r][kk] = v;
  }
  #pragma unroll
  for (int s = 0; s < 8; ++s) {
    int idx = tid + s * 256;
    int kk = idx >> 6, cc = idx & 63;
    float a  = Wk[(size_t)(2 * kk)     * G4 + n0 + cc];
    float b2 = Wk[(size_t)(2 * kk + 1) * G4 + n0 + cc];
    f16x2 v; v.x = (f16)a; v.y = (f16)b2;
    Wh[cc][kk] = v;
  }
  __syncthreads();

  const int tx = tid & 15, ty = tid >> 4;
  float acc[4][4] = {{0.f}};
  #pragma unroll 4
  for (int kk = 0; kk < 32; ++kk) {
    f16x2 a0 = Eh[ty*4+0][kk], a1 = Eh[ty*4+1][kk], a2 = Eh[ty*4+2][kk], a3 = Eh[ty*4+3][kk];
    f16x2 w0 = Wh[tx*4+0][kk], w1 = Wh[tx*4+1][kk], w2 = Wh[tx*4+2][kk], w3 = Wh[tx*4+3][kk];
    acc[0][0] = FDOT2(a0, w0, acc[0][0]); acc[0][1] = FDOT2(a0, w1, acc[0][1]);
    acc[0][2] = FDOT2(a0, w2, acc[0][2]); acc[0][3] = FDOT2(a0, w3, acc[0][3]);
    acc[1][0] = FDOT2(a1, w0, acc[1][0]); acc[1][1] = FDOT2(a1, w1, acc[1][1]);
    acc[1][2] = FDOT2(a1, w2, acc[1][2]); acc[1][3] = FDOT2(a1, w3, acc[1][3]);
    acc[2][0] = FDOT2(a2, w0, acc[2][0]); acc[2][1] = FDOT2(a2, w1, acc[2][1]);
    acc[2][2] = FDOT2(a2, w2, acc[2][2]); acc[2][3] = FDOT2(a2, w3, acc[2][3]);
    acc[3][0] = FDOT2(a3, w0, acc[3][0]); acc[3][1] = FDOT2(a3, w1, acc[3][1]);
    acc[3][2] = FDOT2(a3, w2, acc[3][2]); acc[3][3] = FDOT2(a3, w3, acc[3][3]);
  }
  float bv[4];
  #pragma unroll
  for (int jj = 0; jj < 4; ++jj) bv[jj] = bias[n0 + tx*4 + jj];
  #pragma unroll
  for (int i = 0; i < 4; ++i) {
    int row = m0 + ty*4 + i;
    if (row < VOCAB) {
      #pragma unroll
      for (int jj = 0; jj < 4; ++jj)
        G[(size_t)row * G4 + n0 + tx*4 + jj] = (f16)(acc[i][jj] + bv[jj]);
    }
  }
}

// ---------------------------------------------------------------------------
// Kernel B: MFMA LSTM. One block = 16 batches x 1 dir. Grid (16, 2), 512 thr.
// z(16x512) = h(16x128) @ Wr + G[tok]  via mfma_f32_16x16x32_f16.
// Wave w owns hidden cols [16w,16w+16): its 4 gate-tiles are cols {128g+16w},
// so after MFMA each lane holds zi/zf/zg/zo for (batch 4q+i, hid 16w+(l&15))
// entirely in registers. c-state in 4 VGPRs. h via 4KB double-buffered
// XOR-swizzled LDS (1 barrier/step). Logit partials fused on waves 0,1.
// Fragment layout: A lane l = (m=l&15, k=(l>>4)*8+j contiguous); B lane l =
// (n=l&15, k=(l>>4)*8+j); C/D col=l&15, row=(l>>4)*4+reg (m89-verified).
// ---------------------------------------------------------------------------
__global__ __launch_bounds__(512)
void lstm_mfma_kernel(const int* __restrict__ tokens,
                      const f16* __restrict__ G_f, const f16* __restrict__ G_b,
                      const float* __restrict__ Wr_f, const float* __restrict__ Wr_b,
                      const float* __restrict__ Wd, const float* __restrict__ bd,
                      float* __restrict__ Lf, float* __restrict__ Lb) {
  const int bg  = blockIdx.x;
  const int dir = blockIdx.y;
  const int b0  = bg * 16;
  const f16* __restrict__ G = dir ? G_b : G_f;
  const float* __restrict__ Wr = dir ? Wr_b : Wr_f;
  float* __restrict__ Lout = dir ? Lb : Lf;

  const int tid = threadIdx.x;
  const int w = tid >> 6;          // wave 0..7
  const int l = tid & 63;
  const int mn = l & 15;           // tile row/col index
  const int q  = l >> 4;           // k-group / batch-row group

  __shared__ __align__(16) f16 h_lds[2][16 * HID];   // 2 x 4KB, swizzled
  __shared__ int tokT[SEQ][16];                      // 32KB transposed tokens

  for (int idx = tid; idx < 16 * SEQ; idx += 512) {
    int r = idx >> 9, t = idx & 511;
    tokT[t][r] = tokens[(size_t)(b0 + r) * SEQ + t];
  }
  for (int idx = tid; idx < 1024; idx += 512)
    ((unsigned*)h_lds[0])[idx] = 0u;

  // B fragments: Wr[k][128g + 16w + mn], k = 32s + 8q + j   (64 VGPRs)
  f16x8 bw[4][4];
  #pragma unroll
  for (int g = 0; g < 4; ++g) {
    #pragma unroll
    for (int s = 0; s < 4; ++s) {
      f16x8 v;
      const int colv = 128 * g + 16 * w + mn;
      #pragma unroll
      for (int j = 0; j < 8; ++j)
        v[j] = (f16)Wr[(size_t)(32 * s + 8 * q + j) * G4 + colv];
      bw[g][s] = v;
    }
  }
  // Wd fragments (waves 0,1): tag tile 16w+mn, k over this dir's 128 rows
  f16x8 wdf[4];
  float bdv = 0.0f;
  if (w < 2) {
    #pragma unroll
    for (int s = 0; s < 4; ++s) {
      f16x8 v;
      #pragma unroll
      for (int j = 0; j < 8; ++j)
        v[j] = (f16)Wd[(size_t)(128 * dir + 32 * s + 8 * q + j) * TAGS + 16 * w + mn];
      wdf[s] = v;
    }
    if (dir == 0) bdv = bd[16 * w + mn];
  }

  float cst[4] = {0.f, 0.f, 0.f, 0.f};
  __syncthreads();

  // G prefetch for step 0
  const int t0 = dir ? (SEQ - 1) : 0;
  f16 gc[4][4];   // [gate][i]
  #pragma unroll
  for (int i = 0; i < 4; ++i) {
    const f16* gp = G + (size_t)tokT[t0][4 * q + i] * G4 + 16 * w + mn;
    #pragma unroll
    for (int g = 0; g < 4; ++g) gc[g][i] = gp[128 * g];
  }

  const int swz = (mn & 7) << 4;
  const int chb = (16 * w + mn) * 2;   // hidden col byte offset (pre-swizzle)

  for (int s = 0; s < SEQ; ++s) {
    const int t  = dir ? (SEQ - 1 - s) : s;
    const int sn = (s < SEQ - 1) ? s + 1 : s;
    const int tn = dir ? (SEQ - 1 - sn) : sn;
    const char* hrd = (const char*)h_lds[s & 1];
    char* hwr = (char*)h_lds[(s + 1) & 1];

    // A fragments from swizzled h
    f16x8 a[4];
    #pragma unroll
    for (int ks = 0; ks < 4; ++ks) {
      int off = mn * 256 + ((64 * ks + 16 * q) ^ swz);
      a[ks] = *(const f16x8*)(hrd + off);
    }

    // prefetch next-step G (independent of h)
    f16 gn[4][4];
    #pragma unroll
    for (int i = 0; i < 4; ++i) {
      const f16* gp = G + (size_t)tokT[tn][4 * q + i] * G4 + 16 * w + mn;
      #pragma unroll
      for (int g = 0; g < 4; ++g) gn[g][i] = gp[128 * g];
    }

    // z = h @ Wr  (4 gate tiles x 4 k-steps)
    f32x4 acc[4];
    #pragma unroll
    for (int g = 0; g < 4; ++g) {
      f32x4 z = {0.f, 0.f, 0.f, 0.f};
      #pragma unroll
      for (int ks = 0; ks < 4; ++ks)
        z = __builtin_amdgcn_mfma_f32_16x16x32_f16(a[ks], bw[g][ks], z, 0, 0, 0);
      acc[g] = z;
    }

    // fused logit partials (h slice @ Wd half), waves 0,1
    if (w < 2) {
      f32x4 la = {0.f, 0.f, 0.f, 0.f};
      #pragma unroll
      for (int ks = 0; ks < 4; ++ks)
        la = __builtin_amdgcn_mfma_f32_16x16x32_f16(a[ks], wdf[ks], la, 0, 0, 0);
      #pragma unroll
      for (int i = 0; i < 4; ++i)
        Lout[((size_t)(b0 + 4 * q + i) * SEQ + t) * TAGS + 16 * w + mn] = la[i] + bdv;
    }

    // gates (all in registers)
    f16 hv[4];
    #pragma unroll
    for (int i = 0; i < 4; ++i) {
      float zi = acc[0][i] + (float)gc[0][i];
      float zf = acc[1][i] + (float)gc[1][i];
      float zg = acc[2][i] + (float)gc[2][i];
      float zo = acc[3][i] + (float)gc[3][i];
      float cc = fsig(zf) * cst[i] + fsig(zi) * ftanh(zg);
      cst[i] = cc;
      hv[i] = (f16)(fsig(zo) * ftanh(cc));
    }
    #pragma unroll
    for (int g = 0; g < 4; ++g) {
      #pragma unroll
      for (int i = 0; i < 4; ++i) gc[g][i] = gn[g][i];
    }

    // write h to the OTHER buffer (no reader this step), then one barrier
    #pragma unroll
    for (int i = 0; i < 4; ++i) {
      int r = 4 * q + i;
      int off = r * 256 + (chb ^ ((r & 7) << 4));
      *(f16*)(hwr + off) = hv[i];
    }
    __syncthreads();
  }
}

// ---------------------------------------------------------------------------
// Kernel C: CRF log-likelihood. One wave per batch element. L = Lf + Lb
// (bd already folded into Lf). Transition column in registers; tree max/sum.
// ---------------------------------------------------------------------------
__global__ __launch_bounds__(64)
void crf_kernel(const float* __restrict__ Lf,
                const float* __restrict__ Lb,
                const float* __restrict__ trans,
                const int* __restrict__ labels,
                float* __restrict__ out) {
  const int b = blockIdx.x;
  const int lane = threadIdx.x;
  const int k  = lane & 31;
  const int jh = lane >> 5;

  __shared__ float tr[TAGS * TAGS];
  __shared__ float alpha[TAGS];

  for (int i = lane; i < TAGS * TAGS; i += 64) tr[i] = trans[i];

  // per-lane transition column: trr[i] = trans[jh*16+i][k]
  float trr[16];
  #pragma unroll
  for (int i = 0; i < 16; ++i) trr[i] = trans[(jh * 16 + i) * TAGS + k];

  const size_t base0 = (size_t)b * SEQ * TAGS;

  if (lane < TAGS) alpha[k] = Lf[base0 + k] + Lb[base0 + k];
  __syncthreads();

  float nxt = 0.f;
  if (lane < TAGS) nxt = Lf[base0 + TAGS + k] + Lb[base0 + TAGS + k];

  for (int t = 1; t < SEQ; ++t) {
    float cur = nxt;
    if (t + 1 < SEQ && lane < TAGS) {
      size_t idx = base0 + (size_t)(t + 1) * TAGS + k;
      nxt = Lf[idx] + Lb[idx];
    }

    float v[16], u[16];
    #pragma unroll
    for (int i = 0; i < 16; ++i) {
      v[i] = alpha[jh * 16 + i] + trr[i];
      u[i] = v[i];
    }
    #pragma unroll
    for (int st = 8; st >= 1; st >>= 1)
      #pragma unroll
      for (int i = 0; i < 8; ++i)
        if (i < st) u[i] = fmaxf(u[i], u[i + st]);
    float m = u[0];

    float e[16];
    #pragma unroll
    for (int i = 0; i < 16; ++i) e[i] = __expf(v[i] - m);
    #pragma unroll
    for (int st = 8; st >= 1; st >>= 1)
      #pragma unroll
      for (int i = 0; i < 8; ++i)
        if (i < st) e[i] += e[i + st];
    float ssum = e[0];

    float m2 = __shfl_xor(m, 32);
    float s2 = __shfl_xor(ssum, 32);
    float mm = fmaxf(m, m2);
    float stot = ssum * __expf(m - mm) + s2 * __expf(m2 - mm);
    float anew = mm + __logf(stot) + cur;
    __syncthreads();
    if (lane < TAGS) alpha[k] = anew;
    __syncthreads();
  }

  float av = (lane < TAGS) ? alpha[k] : -1e30f;
  float m = av;
  #pragma unroll
  for (int off = 1; off <= 16; off <<= 1) m = fmaxf(m, __shfl_xor(m, off));
  float ex = (lane < TAGS) ? __expf(av - m) : 0.0f;
  float s = ex;
  #pragma unroll
  for (int off = 1; off <= 32; off <<= 1) s += __shfl_xor(s, off);

  const int* lab = labels + (size_t)b * SEQ;
  float uacc = 0.f, bacc = 0.f;
  for (int t = lane; t < SEQ; t += 64) {
    int l0 = lab[t];
    size_t idx = base0 + (size_t)t * TAGS + l0;
    uacc += Lf[idx] + Lb[idx];
    if (t + 1 < SEQ) bacc += tr[l0 * TAGS + lab[t + 1]];
  }
  float red = uacc + bacc;
  #pragma unroll
  for (int off = 1; off <= 32; off <<= 1) red += __shfl_xor(red, off);

  if (lane == 0) out[b] = red - (m + __logf(s));
}

// ---------------------------------------------------------------------------
// Kernel D: copy transition matrix to the second output slot.
// ---------------------------------------------------------------------------
__global__ void copy_trans_kernel(const float* __restrict__ trans,
                                  float* __restrict__ out) {
  int i = blockIdx.x * blockDim.x + threadIdx.x;
  if (i < TAGS * TAGS) out[i] = trans[i];
}

extern "C" void kernel_launch(void* const* d_in, const int* in_sizes, int n_in,
                              void* d_out, int out_size, void* d_ws, size_t ws_size,
                              hipStream_t stream) {
  const int*   inputs = (const int*)  d_in[0];
  const int*   labels = (const int*)  d_in[1];
  const float* E      = (const float*)d_in[2];
  const float* Wk_f   = (const float*)d_in[3];
  const float* Wr_f   = (const float*)d_in[4];
  const float* b_f    = (const float*)d_in[5];
  const float* Wk_b   = (const float*)d_in[6];
  const float* Wr_b   = (const float*)d_in[7];
  const float* b_b    = (const float*)d_in[8];
  const float* Wd     = (const float*)d_in[9];
  const float* bd     = (const float*)d_in[10];
  const float* trans  = (const float*)d_in[11];
  float* out = (float*)d_out;

  char* ws = (char*)d_ws;
  const size_t G_ELEMS = (size_t)VOCAB * G4;            // 25,600,512 f16 each dir
  f16* G_f = (f16*)ws;
  f16* G_b = G_f + G_ELEMS;
  float* Lfp = (float*)(ws + 2 * G_ELEMS * sizeof(f16));
  float* Lbp = Lfp + (size_t)BATCH * SEQ * TAGS;

  dim3 ggrid((VOCAB + 63) / 64, G4 / 64, 2);
  gtab_kernel<<<ggrid, 256, 0, stream>>>(E, Wk_f, b_f, Wk_b, b_b, G_f, G_b);

  lstm_mfma_kernel<<<dim3(BATCH / 16, 2), 512, 0, stream>>>(
      inputs, G_f, G_b, Wr_f, Wr_b, Wd, bd, Lfp, Lbp);

  crf_kernel<<<BATCH, 64, 0, stream>>>(Lfp, Lbp, trans, labels, out);

  copy_trans_kernel<<<(TAGS * TAGS + 255) / 256, 256, 0, stream>>>(trans, out + BATCH);
}

// Round 6
// 1221.931 us; speedup vs baseline: 1.1358x; 1.1358x over previous
//
#include <hip/hip_runtime.h>
#include <hip/hip_bf16.h>
#include <cstdint>
#include <cstddef>

#define VOCAB 50001
#define EMB 64
#define HID 128
#define G4  512   // 4*HID
#define TAGS 32
#define BATCH 256
#define SEQ 512

typedef _Float16 f16;
typedef _Float16 f16x2 __attribute__((ext_vector_type(2)));
typedef _Float16 f16x4 __attribute__((ext_vector_type(4)));
typedef _Float16 f16x8 __attribute__((ext_vector_type(8)));
typedef float f32x4 __attribute__((ext_vector_type(4)));

#if __has_builtin(__builtin_amdgcn_fdot2)
__device__ __forceinline__ float FDOT2(f16x2 a, f16x2 b, float c) {
  return __builtin_amdgcn_fdot2(a, b, c, false);
}
#else
__device__ __forceinline__ float FDOT2(f16x2 a, f16x2 b, float c) {
  return c + (float)a.x * (float)b.x + (float)a.y * (float)b.y;
}
#endif

__device__ __forceinline__ float fsig(float x) {
  return 1.0f / (1.0f + __expf(-x));
}
__device__ __forceinline__ float ftanh(float x) {
  float e = __expf(2.0f * x);
  return 1.0f - 2.0f / (e + 1.0f);
}

#define MFMA16(A, B, C) __builtin_amdgcn_mfma_f32_16x16x32_f16((A), (B), (C), 0, 0, 0)

// ---------------------------------------------------------------------------
// Kernel A: gate tables, GATE-INTERLEAVED layout:
//   Gi[v][hid*4 + gate] = sum_k E[v,k]*Wk[k, gate*128+hid] + b[gate*128+hid]
// so the LSTM reads all 4 gates of one hid as a single 8B load.
// ---------------------------------------------------------------------------
__global__ __launch_bounds__(256)
void gtab_kernel(const float* __restrict__ E,
                 const float* __restrict__ Wk_f, const float* __restrict__ b_f,
                 const float* __restrict__ Wk_b, const float* __restrict__ b_b,
                 f16* __restrict__ G_f, f16* __restrict__ G_b) {
  const int dir = blockIdx.z;
  const float* __restrict__ Wk   = dir ? Wk_b : Wk_f;
  const float* __restrict__ bias = dir ? b_b  : b_f;
  f16* __restrict__ G = dir ? G_b : G_f;

  __shared__ f16x2 Eh[64][33];
  __shared__ f16x2 Wh[64][33];

  const int m0 = blockIdx.x * 64;
  const int n0 = blockIdx.y * 64;
  const int tid = threadIdx.x;

  #pragma unroll
  for (int s = 0; s < 8; ++s) {
    int idx = tid + s * 256;
    int r = idx >> 5, kk = idx & 31;
    int row = m0 + r;
    float2 ev;
    if (row < VOCAB) ev = *(const float2*)(E + (size_t)row * EMB + 2 * kk);
    else { ev.x = 0.f; ev.y = 0.f; }
    f16x2 v; v.x = (f16)ev.x; v.y = (f16)ev.y;
    Eh[r][kk] = v;
  }
  #pragma unroll
  for (int s = 0; s < 8; ++s) {
    int idx = tid + s * 256;
    int kk = idx >> 6, cc = idx & 63;
    float a  = Wk[(size_t)(2 * kk)     * G4 + n0 + cc];
    float b2 = Wk[(size_t)(2 * kk + 1) * G4 + n0 + cc];
    f16x2 v; v.x = (f16)a; v.y = (f16)b2;
    Wh[cc][kk] = v;
  }
  __syncthreads();

  const int tx = tid & 15, ty = tid >> 4;
  float acc[4][4] = {{0.f}};
  #pragma unroll 4
  for (int kk = 0; kk < 32; ++kk) {
    f16x2 a0 = Eh[ty*4+0][kk], a1 = Eh[ty*4+1][kk], a2 = Eh[ty*4+2][kk], a3 = Eh[ty*4+3][kk];
    f16x2 w0 = Wh[tx*4+0][kk], w1 = Wh[tx*4+1][kk], w2 = Wh[tx*4+2][kk], w3 = Wh[tx*4+3][kk];
    acc[0][0] = FDOT2(a0, w0, acc[0][0]); acc[0][1] = FDOT2(a0, w1, acc[0][1]);
    acc[0][2] = FDOT2(a0, w2, acc[0][2]); acc[0][3] = FDOT2(a0, w3, acc[0][3]);
    acc[1][0] = FDOT2(a1, w0, acc[1][0]); acc[1][1] = FDOT2(a1, w1, acc[1][1]);
    acc[1][2] = FDOT2(a1, w2, acc[1][2]); acc[1][3] = FDOT2(a1, w3, acc[1][3]);
    acc[2][0] = FDOT2(a2, w0, acc[2][0]); acc[2][1] = FDOT2(a2, w1, acc[2][1]);
    acc[2][2] = FDOT2(a2, w2, acc[2][2]); acc[2][3] = FDOT2(a2, w3, acc[2][3]);
    acc[3][0] = FDOT2(a3, w0, acc[3][0]); acc[3][1] = FDOT2(a3, w1, acc[3][1]);
    acc[3][2] = FDOT2(a3, w2, acc[3][2]); acc[3][3] = FDOT2(a3, w3, acc[3][3]);
  }
  float bv[4];
  #pragma unroll
  for (int jj = 0; jj < 4; ++jj) bv[jj] = bias[n0 + tx*4 + jj];
  #pragma unroll
  for (int i = 0; i < 4; ++i) {
    int row = m0 + ty*4 + i;
    if (row < VOCAB) {
      #pragma unroll
      for (int jj = 0; jj < 4; ++jj) {
        int c = n0 + tx*4 + jj;   // original col: gate = c>>7, hid = c&127
        G[(size_t)row * G4 + ((c & 127) << 2) + (c >> 7)] = (f16)(acc[i][jj] + bv[jj]);
      }
    }
  }
}

// ---------------------------------------------------------------------------
// Kernel B: MFMA LSTM with 4-deep G-prefetch and non-draining barriers.
// One block = 16 batches x 1 dir, grid (16,2), 512 thr (8 waves).
// Wave w owns hidden cols [16w,16w+16). Per step per lane: 4x 8B G loads
// (all 4 gates of one hid), issued 4 steps ahead into named register
// buffers gA..gD (statically indexed). Barrier = lgkmcnt(0)+s_barrier only,
// so prefetch loads stay in flight across steps.
// ---------------------------------------------------------------------------
__global__ __launch_bounds__(512)
void lstm_mfma_kernel(const int* __restrict__ tokens,
                      const f16* __restrict__ G_f, const f16* __restrict__ G_b,
                      const float* __restrict__ Wr_f, const float* __restrict__ Wr_b,
                      const float* __restrict__ Wd, const float* __restrict__ bd,
                      float* __restrict__ Lf, float* __restrict__ Lb) {
  const int bg  = blockIdx.x;
  const int dir = blockIdx.y;
  const int b0  = bg * 16;
  const f16* __restrict__ G = dir ? G_b : G_f;
  const float* __restrict__ Wr = dir ? Wr_b : Wr_f;
  float* __restrict__ Lout = dir ? Lb : Lf;

  const int tid = threadIdx.x;
  const int w = tid >> 6;
  const int l = tid & 63;
  const int mn = l & 15;
  const int q  = l >> 4;

  __shared__ __align__(16) f16 h_lds[2][16 * HID];
  __shared__ int tokT[SEQ][16];

  for (int idx = tid; idx < 16 * SEQ; idx += 512) {
    int r = idx >> 9, t = idx & 511;
    tokT[t][r] = tokens[(size_t)(b0 + r) * SEQ + t];
  }
  for (int idx = tid; idx < 1024; idx += 512)
    ((unsigned*)h_lds[0])[idx] = 0u;

  // B fragments: Wr[k][128g + 16w + mn], k = 32s + 8q + j
  f16x8 bw[4][4];
  #pragma unroll
  for (int g = 0; g < 4; ++g) {
    #pragma unroll
    for (int s = 0; s < 4; ++s) {
      f16x8 v;
      const int colv = 128 * g + 16 * w + mn;
      #pragma unroll
      for (int j = 0; j < 8; ++j)
        v[j] = (f16)Wr[(size_t)(32 * s + 8 * q + j) * G4 + colv];
      bw[g][s] = v;
    }
  }
  // Wd fragments (waves 0,1)
  f16x8 wdf0{}, wdf1{}, wdf2{}, wdf3{};
  float bdv = 0.0f;
  if (w < 2) {
    #pragma unroll
    for (int j = 0; j < 8; ++j) {
      wdf0[j] = (f16)Wd[(size_t)(128 * dir +  0 + 8 * q + j) * TAGS + 16 * w + mn];
      wdf1[j] = (f16)Wd[(size_t)(128 * dir + 32 + 8 * q + j) * TAGS + 16 * w + mn];
      wdf2[j] = (f16)Wd[(size_t)(128 * dir + 64 + 8 * q + j) * TAGS + 16 * w + mn];
      wdf3[j] = (f16)Wd[(size_t)(128 * dir + 96 + 8 * q + j) * TAGS + 16 * w + mn];
    }
    if (dir == 0) bdv = bd[16 * w + mn];
  }

  float cst0 = 0.f, cst1 = 0.f, cst2 = 0.f, cst3 = 0.f;
  const int swz = (mn & 7) << 4;
  const int chb = (16 * w + mn) * 2;
  const int hid4 = (16 * w + mn) * 4;

  __syncthreads();

#define TT(S) (dir ? (SEQ - 1 - (S)) : (S))

#define LOADG(S, GA, GB, GC, GD) do {                                          \
    const int _tt = TT(S);                                                     \
    int4 _tk = *(const int4*)&tokT[_tt][4 * q];                                \
    GA = *(const uint2*)(G + (size_t)_tk.x * G4 + hid4);                       \
    GB = *(const uint2*)(G + (size_t)_tk.y * G4 + hid4);                       \
    GC = *(const uint2*)(G + (size_t)_tk.z * G4 + hid4);                       \
    GD = *(const uint2*)(G + (size_t)_tk.w * G4 + hid4);                       \
  } while (0)

#define GATE(I, GV) {                                                          \
    f16x4 _v = __builtin_bit_cast(f16x4, GV);                                  \
    float _zi = z0[I] + (float)_v[0];                                          \
    float _zf = z1[I] + (float)_v[1];                                          \
    float _zg = z2[I] + (float)_v[2];                                          \
    float _zo = z3[I] + (float)_v[3];                                          \
    float _cc = fsig(_zf) * cst##I + fsig(_zi) * ftanh(_zg);                   \
    cst##I = _cc;                                                              \
    f16 _hv = (f16)(fsig(_zo) * ftanh(_cc));                                   \
    const int _rr = 4 * q + I;                                                 \
    *(f16*)(hwr + _rr * 256 + (chb ^ ((_rr & 7) << 4))) = _hv;                 \
  }

#define STEP(S, GA, GB, GC, GD) do {                                           \
    const int _s = (S);                                                        \
    const int _t = TT(_s);                                                     \
    const char* hrd = (const char*)h_lds[_s & 1];                              \
    char* hwr = (char*)h_lds[(_s + 1) & 1];                                    \
    f16x8 a0 = *(const f16x8*)(hrd + mn * 256 + ((16 * q      ) ^ swz));       \
    f16x8 a1 = *(const f16x8*)(hrd + mn * 256 + ((16 * q +  64) ^ swz));       \
    f16x8 a2 = *(const f16x8*)(hrd + mn * 256 + ((16 * q + 128) ^ swz));       \
    f16x8 a3 = *(const f16x8*)(hrd + mn * 256 + ((16 * q + 192) ^ swz));       \
    f32x4 z0 = {0.f,0.f,0.f,0.f}, z1 = {0.f,0.f,0.f,0.f};                      \
    f32x4 z2 = {0.f,0.f,0.f,0.f}, z3 = {0.f,0.f,0.f,0.f};                      \
    z0 = MFMA16(a0, bw[0][0], z0); z0 = MFMA16(a1, bw[0][1], z0);              \
    z0 = MFMA16(a2, bw[0][2], z0); z0 = MFMA16(a3, bw[0][3], z0);              \
    z1 = MFMA16(a0, bw[1][0], z1); z1 = MFMA16(a1, bw[1][1], z1);              \
    z1 = MFMA16(a2, bw[1][2], z1); z1 = MFMA16(a3, bw[1][3], z1);              \
    z2 = MFMA16(a0, bw[2][0], z2); z2 = MFMA16(a1, bw[2][1], z2);              \
    z2 = MFMA16(a2, bw[2][2], z2); z2 = MFMA16(a3, bw[2][3], z2);              \
    z3 = MFMA16(a0, bw[3][0], z3); z3 = MFMA16(a1, bw[3][1], z3);              \
    z3 = MFMA16(a2, bw[3][2], z3); z3 = MFMA16(a3, bw[3][3], z3);              \
    if (w < 2) {                                                               \
      f32x4 la = {0.f,0.f,0.f,0.f};                                            \
      la = MFMA16(a0, wdf0, la); la = MFMA16(a1, wdf1, la);                    \
      la = MFMA16(a2, wdf2, la); la = MFMA16(a3, wdf3, la);                    \
      Lout[((size_t)(b0 + 4*q + 0) * SEQ + _t) * TAGS + 16*w + mn] = la[0] + bdv; \
      Lout[((size_t)(b0 + 4*q + 1) * SEQ + _t) * TAGS + 16*w + mn] = la[1] + bdv; \
      Lout[((size_t)(b0 + 4*q + 2) * SEQ + _t) * TAGS + 16*w + mn] = la[2] + bdv; \
      Lout[((size_t)(b0 + 4*q + 3) * SEQ + _t) * TAGS + 16*w + mn] = la[3] + bdv; \
    }                                                                          \
    GATE(0, GA) GATE(1, GB) GATE(2, GC) GATE(3, GD)                            \
    asm volatile("s_waitcnt lgkmcnt(0)\n\ts_barrier" ::: "memory");            \
  } while (0)

  uint2 gA0, gA1, gA2, gA3, gB0, gB1, gB2, gB3;
  uint2 gC0, gC1, gC2, gC3, gD0, gD1, gD2, gD3;
  LOADG(0, gA0, gA1, gA2, gA3);
  LOADG(1, gB0, gB1, gB2, gB3);
  LOADG(2, gC0, gC1, gC2, gC3);
  LOADG(3, gD0, gD1, gD2, gD3);

  for (int it = 0; it < SEQ / 4; ++it) {
    const int s = 4 * it;
    STEP(s + 0, gA0, gA1, gA2, gA3);
    { int sc = (s + 4 < SEQ) ? s + 4 : SEQ - 1; LOADG(sc, gA0, gA1, gA2, gA3); }
    STEP(s + 1, gB0, gB1, gB2, gB3);
    { int sc = (s + 5 < SEQ) ? s + 5 : SEQ - 1; LOADG(sc, gB0, gB1, gB2, gB3); }
    STEP(s + 2, gC0, gC1, gC2, gC3);
    { int sc = (s + 6 < SEQ) ? s + 6 : SEQ - 1; LOADG(sc, gC0, gC1, gC2, gC3); }
    STEP(s + 3, gD0, gD1, gD2, gD3);
    { int sc = (s + 7 < SEQ) ? s + 7 : SEQ - 1; LOADG(sc, gD0, gD1, gD2, gD3); }
  }
#undef STEP
#undef GATE
#undef LOADG
#undef TT
}

// ---------------------------------------------------------------------------
// Kernel C: CRF log-likelihood, alpha fully in registers (no LDS / barriers
// in the recurrence). lane k&31 holds alpha_k, duplicated across half-waves;
// cross-lane gather via __shfl; j-space split between the two halves.
// ---------------------------------------------------------------------------
__global__ __launch_bounds__(64)
void crf_kernel(const float* __restrict__ Lf,
                const float* __restrict__ Lb,
                const float* __restrict__ trans,
                const int* __restrict__ labels,
                float* __restrict__ out) {
  const int b = blockIdx.x;
  const int lane = threadIdx.x;
  const int k  = lane & 31;
  const int jh = lane >> 5;
  const int hb = lane & 32;

  __shared__ float tr[TAGS * TAGS];
  for (int i = lane; i < TAGS * TAGS; i += 64) tr[i] = trans[i];
  __syncthreads();

  float trr[16];
  #pragma unroll
  for (int i = 0; i < 16; ++i) trr[i] = trans[(jh * 16 + i) * TAGS + k];

  const size_t base0 = (size_t)b * SEQ * TAGS;
  float alpha = Lf[base0 + k] + Lb[base0 + k];
  float nxt   = Lf[base0 + TAGS + k] + Lb[base0 + TAGS + k];

  for (int t = 1; t < SEQ; ++t) {
    float cur = nxt;
    if (t + 1 < SEQ) {
      size_t idx = base0 + (size_t)(t + 1) * TAGS + k;
      nxt = Lf[idx] + Lb[idx];
    }

    float v[16];
    #pragma unroll
    for (int i = 0; i < 16; ++i)
      v[i] = __shfl(alpha, hb + jh * 16 + i) + trr[i];

    float u[16];
    #pragma unroll
    for (int i = 0; i < 16; ++i) u[i] = v[i];
    #pragma unroll
    for (int st = 8; st >= 1; st >>= 1)
      #pragma unroll
      for (int i = 0; i < 8; ++i)
        if (i < st) u[i] = fmaxf(u[i], u[i + st]);
    float m = u[0];

    float e[16];
    #pragma unroll
    for (int i = 0; i < 16; ++i) e[i] = __expf(v[i] - m);
    #pragma unroll
    for (int st = 8; st >= 1; st >>= 1)
      #pragma unroll
      for (int i = 0; i < 8; ++i)
        if (i < st) e[i] += e[i + st];
    float ssum = e[0];

    float m2 = __shfl_xor(m, 32);
    float s2 = __shfl_xor(ssum, 32);
    float mm = fmaxf(m, m2);
    float stot = ssum * __expf(m - mm) + s2 * __expf(m2 - mm);
    alpha = mm + __logf(stot) + cur;
  }

  float m = alpha;
  #pragma unroll
  for (int off = 1; off <= 16; off <<= 1) m = fmaxf(m, __shfl_xor(m, off));
  float ex = (lane < TAGS) ? __expf(alpha - m) : 0.0f;
  float s = ex;
  #pragma unroll
  for (int off = 1; off <= 32; off <<= 1) s += __shfl_xor(s, off);

  const int* lab = labels + (size_t)b * SEQ;
  float uacc = 0.f, bacc = 0.f;
  for (int t = lane; t < SEQ; t += 64) {
    int l0 = lab[t];
    size_t idx = base0 + (size_t)t * TAGS + l0;
    uacc += Lf[idx] + Lb[idx];
    if (t + 1 < SEQ) bacc += tr[l0 * TAGS + lab[t + 1]];
  }
  float red = uacc + bacc;
  #pragma unroll
  for (int off = 1; off <= 32; off <<= 1) red += __shfl_xor(red, off);

  if (lane == 0) out[b] = red - (m + __logf(s));
}

// ---------------------------------------------------------------------------
// Kernel D: copy transition matrix to the second output slot.
// ---------------------------------------------------------------------------
__global__ void copy_trans_kernel(const float* __restrict__ trans,
                                  float* __restrict__ out) {
  int i = blockIdx.x * blockDim.x + threadIdx.x;
  if (i < TAGS * TAGS) out[i] = trans[i];
}

extern "C" void kernel_launch(void* const* d_in, const int* in_sizes, int n_in,
                              void* d_out, int out_size, void* d_ws, size_t ws_size,
                              hipStream_t stream) {
  const int*   inputs = (const int*)  d_in[0];
  const int*   labels = (const int*)  d_in[1];
  const float* E      = (const float*)d_in[2];
  const float* Wk_f   = (const float*)d_in[3];
  const float* Wr_f   = (const float*)d_in[4];
  const float* b_f    = (const float*)d_in[5];
  const float* Wk_b   = (const float*)d_in[6];
  const float* Wr_b   = (const float*)d_in[7];
  const float* b_b    = (const float*)d_in[8];
  const float* Wd     = (const float*)d_in[9];
  const float* bd     = (const float*)d_in[10];
  const float* trans  = (const float*)d_in[11];
  float* out = (float*)d_out;

  char* ws = (char*)d_ws;
  const size_t G_ELEMS = (size_t)VOCAB * G4;            // 25,600,512 f16 each dir
  f16* G_f = (f16*)ws;
  f16* G_b = G_f + G_ELEMS;
  float* Lfp = (float*)(ws + 2 * G_ELEMS * sizeof(f16));
  float* Lbp = Lfp + (size_t)BATCH * SEQ * TAGS;

  dim3 ggrid((VOCAB + 63) / 64, G4 / 64, 2);
  gtab_kernel<<<ggrid, 256, 0, stream>>>(E, Wk_f, b_f, Wk_b, b_b, G_f, G_b);

  lstm_mfma_kernel<<<dim3(BATCH / 16, 2), 512, 0, stream>>>(
      inputs, G_f, G_b, Wr_f, Wr_b, Wd, bd, Lfp, Lbp);

  crf_kernel<<<BATCH, 64, 0, stream>>>(Lfp, Lbp, trans, labels, out);

  copy_trans_kernel<<<(TAGS * TAGS + 255) / 256, 256, 0, stream>>>(trans, out + BATCH);
}

// Round 8
// 811.674 us; speedup vs baseline: 1.7098x; 1.5054x over previous
//
#include <hip/hip_runtime.h>
#include <hip/hip_bf16.h>
#include <cstdint>
#include <cstddef>

#define VOCAB 50001
#define EMB 64
#define HID 128
#define G4  512   // 4*HID
#define TAGS 32
#define BATCH 256
#define SEQ 512

typedef _Float16 f16;
typedef _Float16 f16x2 __attribute__((ext_vector_type(2)));
typedef _Float16 f16x4 __attribute__((ext_vector_type(4)));
typedef _Float16 f16x8 __attribute__((ext_vector_type(8)));
typedef float f32x4 __attribute__((ext_vector_type(4)));

__device__ __forceinline__ float rcpf(float x) { return __builtin_amdgcn_rcpf(x); }

#define MFMA16(A, B, C) __builtin_amdgcn_mfma_f32_16x16x32_f16((A), (B), (C), 0, 0, 0)

// ---------------------------------------------------------------------------
// Kernel A: gate tables via MFMA.  G[v][hid*4+gate] = (E @ Wk + b), f16.
// Tile: 64 vocab-rows x 256 cols (one gate-pair) per block, K=64.
// grid (782, 2, 2dirs), 256 threads (4 waves, wave w = rows 16w..16w+16).
// ---------------------------------------------------------------------------
__global__ __launch_bounds__(256)
void gtab_mfma_kernel(const float* __restrict__ E,
                      const float* __restrict__ Wk_f, const float* __restrict__ b_f,
                      const float* __restrict__ Wk_b, const float* __restrict__ b_b,
                      f16* __restrict__ G_f, f16* __restrict__ G_b) {
  const int dir = blockIdx.z;
  const float* __restrict__ Wk   = dir ? Wk_b : Wk_f;
  const float* __restrict__ bias = dir ? b_b  : b_f;
  f16* __restrict__ G = dir ? G_b : G_f;

  const int m0 = blockIdx.x * 64;
  const int n0 = blockIdx.y * 256;        // 0: gates i,f   256: gates g,o
  const int tid = threadIdx.x;

  __shared__ f16 Eh[64][80];    // A [m][k], +16 pad (bank spread, 16B align)
  __shared__ f16 Bh[256][80];   // B [n][k], +16 pad

  // stage E (64x64 f32 -> f16)
  #pragma unroll
  for (int s = 0; s < 4; ++s) {
    int idx = tid + s * 256;
    int r = idx >> 4, c4 = (idx & 15) * 4;
    int row = m0 + r;
    float4 ev;
    if (row < VOCAB) ev = *(const float4*)(E + (size_t)row * EMB + c4);
    else { ev.x = 0.f; ev.y = 0.f; ev.z = 0.f; ev.w = 0.f; }
    f16x4 v; v[0] = (f16)ev.x; v[1] = (f16)ev.y; v[2] = (f16)ev.z; v[3] = (f16)ev.w;
    *(f16x4*)&Eh[r][c4] = v;
  }
  // stage B transposed: Bh[n][k] = Wk[k][n0+n]
  #pragma unroll
  for (int s = 0; s < 32; ++s) {
    int idx = tid + s * 256;
    int k = idx >> 7, n2 = (idx & 127) * 2;
    float2 wv = *(const float2*)(Wk + (size_t)k * G4 + n0 + n2);
    Bh[n2][k]     = (f16)wv.x;
    Bh[n2 + 1][k] = (f16)wv.y;
  }
  __syncthreads();

  const int w = tid >> 6, l = tid & 63, mn = l & 15, q = l >> 4;
  f16x8 a0 = *(const f16x8*)&Eh[16 * w + mn][8 * q];
  f16x8 a1 = *(const f16x8*)&Eh[16 * w + mn][32 + 8 * q];

  f32x4 acc[16];
  #pragma unroll
  for (int nt = 0; nt < 16; ++nt) {
    f16x8 b0 = *(const f16x8*)&Bh[16 * nt + mn][8 * q];
    f16x8 b1 = *(const f16x8*)&Bh[16 * nt + mn][32 + 8 * q];
    f32x4 z = {0.f, 0.f, 0.f, 0.f};
    z = MFMA16(a0, b0, z);
    z = MFMA16(a1, b1, z);
    acc[nt] = z;
  }

  // epilogue: pair (nt, nt+8) = same hid, adjacent gates -> one f16x2 store
  const int gA = n0 >> 7;   // 0 or 2
  #pragma unroll
  for (int nt = 0; nt < 8; ++nt) {
    int hid = 16 * nt + mn;
    float bv0 = bias[n0 + 16 * nt + mn];
    float bv1 = bias[n0 + 128 + 16 * nt + mn];
    #pragma unroll
    for (int reg = 0; reg < 4; ++reg) {
      int row = m0 + 16 * w + 4 * q + reg;
      if (row < VOCAB) {
        f16x2 v; v.x = (f16)(acc[nt][reg] + bv0); v.y = (f16)(acc[nt + 8][reg] + bv1);
        *(f16x2*)(G + (size_t)row * G4 + hid * 4 + gA) = v;
      }
    }
  }
}

// ---------------------------------------------------------------------------
// Kernel B: MFMA LSTM, division-free gates, 4-deep G prefetch, non-draining
// barrier. One block = 16 batches x 1 dir, grid (16,2), 512 thr (8 waves).
// ---------------------------------------------------------------------------
__global__ __launch_bounds__(512)
void lstm_mfma_kernel(const int* __restrict__ tokens,
                      const f16* __restrict__ G_f, const f16* __restrict__ G_b,
                      const float* __restrict__ Wr_f, const float* __restrict__ Wr_b,
                      const float* __restrict__ Wd, const float* __restrict__ bd,
                      float* __restrict__ Lf, float* __restrict__ Lb) {
  const int bg  = blockIdx.x;
  const int dir = blockIdx.y;
  const int b0  = bg * 16;
  const f16* __restrict__ G = dir ? G_b : G_f;
  const float* __restrict__ Wr = dir ? Wr_b : Wr_f;
  float* __restrict__ Lout = dir ? Lb : Lf;

  const int tid = threadIdx.x;
  const int w = tid >> 6;
  const int l = tid & 63;
  const int mn = l & 15;
  const int q  = l >> 4;

  __shared__ __align__(16) f16 h_lds[2][16 * HID];
  __shared__ int tokT[SEQ][16];

  for (int idx = tid; idx < 16 * SEQ; idx += 512) {
    int r = idx >> 9, t = idx & 511;
    tokT[t][r] = tokens[(size_t)(b0 + r) * SEQ + t];
  }
  for (int idx = tid; idx < 1024; idx += 512)
    ((unsigned*)h_lds[0])[idx] = 0u;

  // B fragments: Wr[k][128g + 16w + mn], k = 32s + 8q + j
  f16x8 bw[4][4];
  #pragma unroll
  for (int g = 0; g < 4; ++g) {
    #pragma unroll
    for (int s = 0; s < 4; ++s) {
      f16x8 v;
      const int colv = 128 * g + 16 * w + mn;
      #pragma unroll
      for (int j = 0; j < 8; ++j)
        v[j] = (f16)Wr[(size_t)(32 * s + 8 * q + j) * G4 + colv];
      bw[g][s] = v;
    }
  }
  // Wd fragments (waves 0,1)
  f16x8 wdf0{}, wdf1{}, wdf2{}, wdf3{};
  float bdv = 0.0f;
  if (w < 2) {
    #pragma unroll
    for (int j = 0; j < 8; ++j) {
      wdf0[j] = (f16)Wd[(size_t)(128 * dir +  0 + 8 * q + j) * TAGS + 16 * w + mn];
      wdf1[j] = (f16)Wd[(size_t)(128 * dir + 32 + 8 * q + j) * TAGS + 16 * w + mn];
      wdf2[j] = (f16)Wd[(size_t)(128 * dir + 64 + 8 * q + j) * TAGS + 16 * w + mn];
      wdf3[j] = (f16)Wd[(size_t)(128 * dir + 96 + 8 * q + j) * TAGS + 16 * w + mn];
    }
    if (dir == 0) bdv = bd[16 * w + mn];
  }

  float cst0 = 0.f, cst1 = 0.f, cst2 = 0.f, cst3 = 0.f;
  const int swz = (mn & 7) << 4;
  const int chb = (16 * w + mn) * 2;
  const int hid4 = (16 * w + mn) * 4;

  __syncthreads();

#define TT(S) (dir ? (SEQ - 1 - (S)) : (S))

#define LOADG(S, GA, GB, GC, GD) do {                                          \
    const int _tt = TT(S);                                                     \
    int4 _tk = *(const int4*)&tokT[_tt][4 * q];                                \
    GA = *(const uint2*)(G + (size_t)_tk.x * G4 + hid4);                       \
    GB = *(const uint2*)(G + (size_t)_tk.y * G4 + hid4);                       \
    GC = *(const uint2*)(G + (size_t)_tk.z * G4 + hid4);                       \
    GD = *(const uint2*)(G + (size_t)_tk.w * G4 + hid4);                       \
  } while (0)

// division-free gates: sig(a)*tanh(b) = (e^{2b}-1) * rcp((1+e^{-a})(e^{2b}+1))
#define GATE(I, GV) {                                                          \
    f16x4 _v = __builtin_bit_cast(f16x4, GV);                                  \
    float _zi = z0[I] + (float)_v[0];                                          \
    float _zf = z1[I] + (float)_v[1];                                          \
    float _zg = z2[I] + (float)_v[2];                                          \
    float _zo = z3[I] + (float)_v[3];                                          \
    float _ei = __expf(-_zi);                                                  \
    float _eg = __expf(fminf(2.f * _zg, 30.f));                                \
    float _sab = (_eg - 1.f) * rcpf((1.f + _ei) * (_eg + 1.f));                \
    float _ef = __expf(-_zf);                                                  \
    float _cc = rcpf(1.f + _ef) * cst##I + _sab;                               \
    cst##I = _cc;                                                              \
    float _eo = __expf(-_zo);                                                  \
    float _ec = __expf(fminf(2.f * _cc, 30.f));                                \
    float _hh = (_ec - 1.f) * rcpf((1.f + _eo) * (_ec + 1.f));                 \
    f16 _hv = (f16)_hh;                                                        \
    const int _rr = 4 * q + I;                                                 \
    *(f16*)(hwr + _rr * 256 + (chb ^ ((_rr & 7) << 4))) = _hv;                 \
  }

#define STEP(S, GA, GB, GC, GD) do {                                           \
    const int _s = (S);                                                        \
    const int _t = TT(_s);                                                     \
    const char* hrd = (const char*)h_lds[_s & 1];                              \
    char* hwr = (char*)h_lds[(_s + 1) & 1];                                    \
    f16x8 a0 = *(const f16x8*)(hrd + mn * 256 + ((16 * q      ) ^ swz));       \
    f16x8 a1 = *(const f16x8*)(hrd + mn * 256 + ((16 * q +  64) ^ swz));       \
    f16x8 a2 = *(const f16x8*)(hrd + mn * 256 + ((16 * q + 128) ^ swz));       \
    f16x8 a3 = *(const f16x8*)(hrd + mn * 256 + ((16 * q + 192) ^ swz));       \
    f32x4 z0 = {0.f,0.f,0.f,0.f}, z1 = {0.f,0.f,0.f,0.f};                      \
    f32x4 z2 = {0.f,0.f,0.f,0.f}, z3 = {0.f,0.f,0.f,0.f};                      \
    z0 = MFMA16(a0, bw[0][0], z0); z0 = MFMA16(a1, bw[0][1], z0);              \
    z0 = MFMA16(a2, bw[0][2], z0); z0 = MFMA16(a3, bw[0][3], z0);              \
    z1 = MFMA16(a0, bw[1][0], z1); z1 = MFMA16(a1, bw[1][1], z1);              \
    z1 = MFMA16(a2, bw[1][2], z1); z1 = MFMA16(a3, bw[1][3], z1);              \
    z2 = MFMA16(a0, bw[2][0], z2); z2 = MFMA16(a1, bw[2][1], z2);              \
    z2 = MFMA16(a2, bw[2][2], z2); z2 = MFMA16(a3, bw[2][3], z2);              \
    z3 = MFMA16(a0, bw[3][0], z3); z3 = MFMA16(a1, bw[3][1], z3);              \
    z3 = MFMA16(a2, bw[3][2], z3); z3 = MFMA16(a3, bw[3][3], z3);              \
    if (w < 2) {                                                               \
      f32x4 la = {0.f,0.f,0.f,0.f};                                            \
      la = MFMA16(a0, wdf0, la); la = MFMA16(a1, wdf1, la);                    \
      la = MFMA16(a2, wdf2, la); la = MFMA16(a3, wdf3, la);                    \
      Lout[((size_t)(b0 + 4*q + 0) * SEQ + _t) * TAGS + 16*w + mn] = la[0] + bdv; \
      Lout[((size_t)(b0 + 4*q + 1) * SEQ + _t) * TAGS + 16*w + mn] = la[1] + bdv; \
      Lout[((size_t)(b0 + 4*q + 2) * SEQ + _t) * TAGS + 16*w + mn] = la[2] + bdv; \
      Lout[((size_t)(b0 + 4*q + 3) * SEQ + _t) * TAGS + 16*w + mn] = la[3] + bdv; \
    }                                                                          \
    GATE(0, GA) GATE(1, GB) GATE(2, GC) GATE(3, GD)                            \
    asm volatile("s_waitcnt lgkmcnt(0)" ::: "memory");                         \
    __builtin_amdgcn_s_barrier();                                              \
  } while (0)

  uint2 gA0, gA1, gA2, gA3, gB0, gB1, gB2, gB3;
  uint2 gC0, gC1, gC2, gC3, gD0, gD1, gD2, gD3;
  LOADG(0, gA0, gA1, gA2, gA3);
  LOADG(1, gB0, gB1, gB2, gB3);
  LOADG(2, gC0, gC1, gC2, gC3);
  LOADG(3, gD0, gD1, gD2, gD3);

  for (int it = 0; it < SEQ / 4; ++it) {
    const int s = 4 * it;
    STEP(s + 0, gA0, gA1, gA2, gA3);
    { int sc = (s + 4 < SEQ) ? s + 4 : SEQ - 1; LOADG(sc, gA0, gA1, gA2, gA3); }
    STEP(s + 1, gB0, gB1, gB2, gB3);
    { int sc = (s + 5 < SEQ) ? s + 5 : SEQ - 1; LOADG(sc, gB0, gB1, gB2, gB3); }
    STEP(s + 2, gC0, gC1, gC2, gC3);
    { int sc = (s + 6 < SEQ) ? s + 6 : SEQ - 1; LOADG(sc, gC0, gC1, gC2, gC3); }
    STEP(s + 3, gD0, gD1, gD2, gD3);
    { int sc = (s + 7 < SEQ) ? s + 7 : SEQ - 1; LOADG(sc, gD0, gD1, gD2, gD3); }
  }
#undef STEP
#undef GATE
#undef LOADG
#undef TT
}

// ---------------------------------------------------------------------------
// Kernel C: CRF log-likelihood, alpha in registers, shfl gather.
// ---------------------------------------------------------------------------
__global__ __launch_bounds__(64)
void crf_kernel(const float* __restrict__ Lf,
                const float* __restrict__ Lb,
                const float* __restrict__ trans,
                const int* __restrict__ labels,
                float* __restrict__ out) {
  const int b = blockIdx.x;
  const int lane = threadIdx.x;
  const int k  = lane & 31;
  const int jh = lane >> 5;
  const int hb = lane & 32;

  __shared__ float tr[TAGS * TAGS];
  for (int i = lane; i < TAGS * TAGS; i += 64) tr[i] = trans[i];
  __syncthreads();

  float trr[16];
  #pragma unroll
  for (int i = 0; i < 16; ++i) trr[i] = trans[(jh * 16 + i) * TAGS + k];

  const size_t base0 = (size_t)b * SEQ * TAGS;
  float alpha = Lf[base0 + k] + Lb[base0 + k];
  float nxt   = Lf[base0 + TAGS + k] + Lb[base0 + TAGS + k];

  for (int t = 1; t < SEQ; ++t) {
    float cur = nxt;
    if (t + 1 < SEQ) {
      size_t idx = base0 + (size_t)(t + 1) * TAGS + k;
      nxt = Lf[idx] + Lb[idx];
    }

    float v[16];
    #pragma unroll
    for (int i = 0; i < 16; ++i)
      v[i] = __shfl(alpha, hb + jh * 16 + i) + trr[i];

    float u[16];
    #pragma unroll
    for (int i = 0; i < 16; ++i) u[i] = v[i];
    #pragma unroll
    for (int st = 8; st >= 1; st >>= 1)
      #pragma unroll
      for (int i = 0; i < 8; ++i)
        if (i < st) u[i] = fmaxf(u[i], u[i + st]);
    float m = u[0];

    float e[16];
    #pragma unroll
    for (int i = 0; i < 16; ++i) e[i] = __expf(v[i] - m);
    #pragma unroll
    for (int st = 8; st >= 1; st >>= 1)
      #pragma unroll
      for (int i = 0; i < 8; ++i)
        if (i < st) e[i] += e[i + st];
    float ssum = e[0];

    float m2 = __shfl_xor(m, 32);
    float s2 = __shfl_xor(ssum, 32);
    float mm = fmaxf(m, m2);
    float stot = ssum * __expf(m - mm) + s2 * __expf(m2 - mm);
    alpha = mm + __logf(stot) + cur;
  }

  float m = alpha;
  #pragma unroll
  for (int off = 1; off <= 16; off <<= 1) m = fmaxf(m, __shfl_xor(m, off));
  float ex = (lane < TAGS) ? __expf(alpha - m) : 0.0f;
  float s = ex;
  #pragma unroll
  for (int off = 1; off <= 32; off <<= 1) s += __shfl_xor(s, off);

  const int* lab = labels + (size_t)b * SEQ;
  float uacc = 0.f, bacc = 0.f;
  for (int t = lane; t < SEQ; t += 64) {
    int l0 = lab[t];
    size_t idx = base0 + (size_t)t * TAGS + l0;
    uacc += Lf[idx] + Lb[idx];
    if (t + 1 < SEQ) bacc += tr[l0 * TAGS + lab[t + 1]];
  }
  float red = uacc + bacc;
  #pragma unroll
  for (int off = 1; off <= 32; off <<= 1) red += __shfl_xor(red, off);

  if (lane == 0) out[b] = red - (m + __logf(s));
}

// ---------------------------------------------------------------------------
// Kernel D: copy transition matrix to the second output slot.
// ---------------------------------------------------------------------------
__global__ void copy_trans_kernel(const float* __restrict__ trans,
                                  float* __restrict__ out) {
  int i = blockIdx.x * blockDim.x + threadIdx.x;
  if (i < TAGS * TAGS) out[i] = trans[i];
}

extern "C" void kernel_launch(void* const* d_in, const int* in_sizes, int n_in,
                              void* d_out, int out_size, void* d_ws, size_t ws_size,
                              hipStream_t stream) {
  const int*   inputs = (const int*)  d_in[0];
  const int*   labels = (const int*)  d_in[1];
  const float* E      = (const float*)d_in[2];
  const float* Wk_f   = (const float*)d_in[3];
  const float* Wr_f   = (const float*)d_in[4];
  const float* b_f    = (const float*)d_in[5];
  const float* Wk_b   = (const float*)d_in[6];
  const float* Wr_b   = (const float*)d_in[7];
  const float* b_b    = (const float*)d_in[8];
  const float* Wd     = (const float*)d_in[9];
  const float* bd     = (const float*)d_in[10];
  const float* trans  = (const float*)d_in[11];
  float* out = (float*)d_out;

  char* ws = (char*)d_ws;
  const size_t G_ELEMS = (size_t)VOCAB * G4;            // 25,600,512 f16 each dir
  f16* G_f = (f16*)ws;
  f16* G_b = G_f + G_ELEMS;
  float* Lfp = (float*)(ws + 2 * G_ELEMS * sizeof(f16));
  float* Lbp = Lfp + (size_t)BATCH * SEQ * TAGS;

  dim3 ggrid((VOCAB + 63) / 64, 2, 2);
  gtab_mfma_kernel<<<ggrid, 256, 0, stream>>>(E, Wk_f, b_f, Wk_b, b_b, G_f, G_b);

  lstm_mfma_kernel<<<dim3(BATCH / 16, 2), 512, 0, stream>>>(
      inputs, G_f, G_b, Wr_f, Wr_b, Wd, bd, Lfp, Lbp);

  crf_kernel<<<BATCH, 64, 0, stream>>>(Lfp, Lbp, trans, labels, out);

  copy_trans_kernel<<<(TAGS * TAGS + 255) / 256, 256, 0, stream>>>(trans, out + BATCH);
}

// Round 9
// 523.146 us; speedup vs baseline: 2.6529x; 1.5515x over previous
//
#include <hip/hip_runtime.h>
#include <hip/hip_bf16.h>
#include <cstdint>
#include <cstddef>

#define VOCAB 50001
#define EMB 64
#define HID 128
#define G4  512   // 4*HID
#define TAGS 32
#define BATCH 256
#define SEQ 512

typedef _Float16 f16;
typedef _Float16 f16x2 __attribute__((ext_vector_type(2)));
typedef _Float16 f16x4 __attribute__((ext_vector_type(4)));
typedef _Float16 f16x8 __attribute__((ext_vector_type(8)));
typedef float f32x4 __attribute__((ext_vector_type(4)));

__device__ __forceinline__ float rcpf(float x) { return __builtin_amdgcn_rcpf(x); }

#define MFMA16(A, B, C) __builtin_amdgcn_mfma_f32_16x16x32_f16((A), (B), (C), 0, 0, 0)

// ---------------------------------------------------------------------------
// Kernel A: gate tables via MFMA (unchanged from R8 — verified correct).
// G[v][hid*4+gate] = (E @ Wk + b), f16, gate-interleaved.
// ---------------------------------------------------------------------------
__global__ __launch_bounds__(256)
void gtab_mfma_kernel(const float* __restrict__ E,
                      const float* __restrict__ Wk_f, const float* __restrict__ b_f,
                      const float* __restrict__ Wk_b, const float* __restrict__ b_b,
                      f16* __restrict__ G_f, f16* __restrict__ G_b) {
  const int dir = blockIdx.z;
  const float* __restrict__ Wk   = dir ? Wk_b : Wk_f;
  const float* __restrict__ bias = dir ? b_b  : b_f;
  f16* __restrict__ G = dir ? G_b : G_f;

  const int m0 = blockIdx.x * 64;
  const int n0 = blockIdx.y * 256;
  const int tid = threadIdx.x;

  __shared__ f16 Eh[64][80];
  __shared__ f16 Bh[256][80];

  #pragma unroll
  for (int s = 0; s < 4; ++s) {
    int idx = tid + s * 256;
    int r = idx >> 4, c4 = (idx & 15) * 4;
    int row = m0 + r;
    float4 ev;
    if (row < VOCAB) ev = *(const float4*)(E + (size_t)row * EMB + c4);
    else { ev.x = 0.f; ev.y = 0.f; ev.z = 0.f; ev.w = 0.f; }
    f16x4 v; v[0] = (f16)ev.x; v[1] = (f16)ev.y; v[2] = (f16)ev.z; v[3] = (f16)ev.w;
    *(f16x4*)&Eh[r][c4] = v;
  }
  #pragma unroll
  for (int s = 0; s < 32; ++s) {
    int idx = tid + s * 256;
    int k = idx >> 7, n2 = (idx & 127) * 2;
    float2 wv = *(const float2*)(Wk + (size_t)k * G4 + n0 + n2);
    Bh[n2][k]     = (f16)wv.x;
    Bh[n2 + 1][k] = (f16)wv.y;
  }
  __syncthreads();

  const int w = tid >> 6, l = tid & 63, mn = l & 15, q = l >> 4;
  f16x8 a0 = *(const f16x8*)&Eh[16 * w + mn][8 * q];
  f16x8 a1 = *(const f16x8*)&Eh[16 * w + mn][32 + 8 * q];

  f32x4 acc[16];
  #pragma unroll
  for (int nt = 0; nt < 16; ++nt) {
    f16x8 b0 = *(const f16x8*)&Bh[16 * nt + mn][8 * q];
    f16x8 b1 = *(const f16x8*)&Bh[16 * nt + mn][32 + 8 * q];
    f32x4 z = {0.f, 0.f, 0.f, 0.f};
    z = MFMA16(a0, b0, z);
    z = MFMA16(a1, b1, z);
    acc[nt] = z;
  }

  const int gA = n0 >> 7;
  #pragma unroll
  for (int nt = 0; nt < 8; ++nt) {
    int hid = 16 * nt + mn;
    float bv0 = bias[n0 + 16 * nt + mn];
    float bv1 = bias[n0 + 128 + 16 * nt + mn];
    #pragma unroll
    for (int reg = 0; reg < 4; ++reg) {
      int row = m0 + 16 * w + 4 * q + reg;
      if (row < VOCAB) {
        f16x2 v; v.x = (f16)(acc[nt][reg] + bv0); v.y = (f16)(acc[nt + 8][reg] + bv1);
        *(f16x2*)(G + (size_t)row * G4 + hid * 4 + gA) = v;
      }
    }
  }
}

// ---------------------------------------------------------------------------
// Kernel B: MFMA LSTM, 2 batches/block x 256 blocks (one per CU).
// 512 thr (8 waves). Wave w owns gate cols {128g+16w+mn}. Per step:
// all waves MFMA z (rows 0-1 valid); q==0 lanes write z to LDS (float2);
// barrier; threads 0-255 (batch=tid>>7, hid=tid&127) read 4 z + G-ring uint2,
// do division-free gates, write h (f16, single 256B buffer); barrier.
// Logits MFMA on waves 6,7. Barriers are lgkmcnt-only (G ring stays in flight).
// ---------------------------------------------------------------------------
__global__ __launch_bounds__(512, 1)
void lstm_mfma_kernel(const int* __restrict__ tokens,
                      const f16* __restrict__ G_f, const f16* __restrict__ G_b,
                      const float* __restrict__ Wr_f, const float* __restrict__ Wr_b,
                      const float* __restrict__ Wd, const float* __restrict__ bd,
                      float* __restrict__ Lf, float* __restrict__ Lb) {
  const int bg  = blockIdx.x;         // 0..127
  const int dir = blockIdx.y;
  const int b0  = bg * 2;
  const f16* __restrict__ G = dir ? G_b : G_f;
  const float* __restrict__ Wr = dir ? Wr_b : Wr_f;
  float* __restrict__ Lout = dir ? Lb : Lf;

  const int tid = threadIdx.x;
  const int w = tid >> 6;
  const int l = tid & 63;
  const int mn = l & 15;
  const int q  = l >> 4;
  const bool gate_thr = (tid < 256);
  const int gb   = (tid >> 7) & 1;    // gate thread's batch
  const int ghid = tid & 127;         // gate thread's hidden index

  __shared__ __align__(16) f16 h_lds[2][HID];        // [batch][hid], 512B
  __shared__ __align__(8)  float z_lds[G4][2];       // [gatecol][batch], 4KB
  __shared__ int tokT[SEQ][2];                       // 4KB

  tokT[tid][0] = tokens[(size_t)(b0 + 0) * SEQ + tid];
  tokT[tid][1] = tokens[(size_t)(b0 + 1) * SEQ + tid];
  if (tid < 128) ((unsigned*)h_lds)[tid] = 0u;       // 256 f16 = 128 dwords

  // B fragments: Wr[k][128g + 16w + mn], k = 32s + 8q + j  (64 VGPRs)
  f16x8 bw[4][4];
  #pragma unroll
  for (int g = 0; g < 4; ++g) {
    #pragma unroll
    for (int s = 0; s < 4; ++s) {
      f16x8 v;
      const int colv = 128 * g + 16 * w + mn;
      #pragma unroll
      for (int j = 0; j < 8; ++j)
        v[j] = (f16)Wr[(size_t)(32 * s + 8 * q + j) * G4 + colv];
      bw[g][s] = v;
    }
  }
  // Wd fragments on waves 6,7 (gate-idle waves): tag = 16*(w-6)+mn
  f16x8 wdf0{}, wdf1{}, wdf2{}, wdf3{};
  float bdv = 0.0f;
  if (w >= 6) {
    const int tag = 16 * (w - 6) + mn;
    #pragma unroll
    for (int j = 0; j < 8; ++j) {
      wdf0[j] = (f16)Wd[(size_t)(128 * dir +  0 + 8 * q + j) * TAGS + tag];
      wdf1[j] = (f16)Wd[(size_t)(128 * dir + 32 + 8 * q + j) * TAGS + tag];
      wdf2[j] = (f16)Wd[(size_t)(128 * dir + 64 + 8 * q + j) * TAGS + tag];
      wdf3[j] = (f16)Wd[(size_t)(128 * dir + 96 + 8 * q + j) * TAGS + tag];
    }
    if (dir == 0) bdv = bd[tag];
  }

  float cst = 0.0f;   // cell state for gate thread's (batch, hid)
  __syncthreads();

#define TT(S) (dir ? (SEQ - 1 - (S)) : (S))

#define LOADG(S, GV) do { if (gate_thr) {                                      \
    int _tk = tokT[TT(S)][gb];                                                 \
    GV = *(const uint2*)(G + (size_t)_tk * G4 + ghid * 4); } } while (0)

#define STEP(S, GV) do {                                                       \
    const int _s = (S);                                                        \
    const int _t = TT(_s);                                                     \
    const char* hbase = (const char*)&h_lds[mn & 1][0];                        \
    f16x8 a0 = *(const f16x8*)(hbase +       16 * q);                          \
    f16x8 a1 = *(const f16x8*)(hbase +  64 + 16 * q);                          \
    f16x8 a2 = *(const f16x8*)(hbase + 128 + 16 * q);                          \
    f16x8 a3 = *(const f16x8*)(hbase + 192 + 16 * q);                          \
    f32x4 z0 = {0.f,0.f,0.f,0.f}, z1 = {0.f,0.f,0.f,0.f};                      \
    f32x4 z2 = {0.f,0.f,0.f,0.f}, z3 = {0.f,0.f,0.f,0.f};                      \
    z0 = MFMA16(a0, bw[0][0], z0); z0 = MFMA16(a1, bw[0][1], z0);              \
    z0 = MFMA16(a2, bw[0][2], z0); z0 = MFMA16(a3, bw[0][3], z0);              \
    z1 = MFMA16(a0, bw[1][0], z1); z1 = MFMA16(a1, bw[1][1], z1);              \
    z1 = MFMA16(a2, bw[1][2], z1); z1 = MFMA16(a3, bw[1][3], z1);              \
    z2 = MFMA16(a0, bw[2][0], z2); z2 = MFMA16(a1, bw[2][1], z2);              \
    z2 = MFMA16(a2, bw[2][2], z2); z2 = MFMA16(a3, bw[2][3], z2);              \
    z3 = MFMA16(a0, bw[3][0], z3); z3 = MFMA16(a1, bw[3][1], z3);              \
    z3 = MFMA16(a2, bw[3][2], z3); z3 = MFMA16(a3, bw[3][3], z3);              \
    if (w >= 6) {                                                              \
      f32x4 la = {0.f,0.f,0.f,0.f};                                            \
      la = MFMA16(a0, wdf0, la); la = MFMA16(a1, wdf1, la);                    \
      la = MFMA16(a2, wdf2, la); la = MFMA16(a3, wdf3, la);                    \
      if (q == 0) {                                                            \
        const int tag = 16 * (w - 6) + mn;                                     \
        Lout[((size_t)(b0 + 0) * SEQ + _t) * TAGS + tag] = la[0] + bdv;        \
        Lout[((size_t)(b0 + 1) * SEQ + _t) * TAGS + tag] = la[1] + bdv;        \
      }                                                                        \
    }                                                                          \
    if (q == 0) {                                                              \
      float2 v0; v0.x = z0[0]; v0.y = z0[1];                                   \
      float2 v1; v1.x = z1[0]; v1.y = z1[1];                                   \
      float2 v2; v2.x = z2[0]; v2.y = z2[1];                                   \
      float2 v3; v3.x = z3[0]; v3.y = z3[1];                                   \
      *(float2*)&z_lds[      16 * w + mn][0] = v0;                             \
      *(float2*)&z_lds[128 + 16 * w + mn][0] = v1;                             \
      *(float2*)&z_lds[256 + 16 * w + mn][0] = v2;                             \
      *(float2*)&z_lds[384 + 16 * w + mn][0] = v3;                             \
    }                                                                          \
    asm volatile("s_waitcnt lgkmcnt(0)" ::: "memory");                         \
    __builtin_amdgcn_s_barrier();                                              \
    if (gate_thr) {                                                            \
      float zi = z_lds[      ghid][gb];                                        \
      float zf = z_lds[128 + ghid][gb];                                        \
      float zg = z_lds[256 + ghid][gb];                                        \
      float zo = z_lds[384 + ghid][gb];                                        \
      f16x4 gv = __builtin_bit_cast(f16x4, GV);                                \
      zi += (float)gv[0]; zf += (float)gv[1];                                  \
      zg += (float)gv[2]; zo += (float)gv[3];                                  \
      float ei = __expf(-zi);                                                  \
      float eg = __expf(fminf(2.f * zg, 30.f));                                \
      float sab = (eg - 1.f) * rcpf((1.f + ei) * (eg + 1.f));                  \
      float ef = __expf(-zf);                                                  \
      float cc = rcpf(1.f + ef) * cst + sab;                                   \
      cst = cc;                                                                \
      float eo = __expf(-zo);                                                  \
      float ec = __expf(fminf(2.f * cc, 30.f));                                \
      float hh = (ec - 1.f) * rcpf((1.f + eo) * (ec + 1.f));                   \
      h_lds[gb][ghid] = (f16)hh;                                               \
    }                                                                          \
    asm volatile("s_waitcnt lgkmcnt(0)" ::: "memory");                         \
    __builtin_amdgcn_s_barrier();                                              \
  } while (0)

  uint2 gA, gB, gC, gD;
  LOADG(0, gA); LOADG(1, gB); LOADG(2, gC); LOADG(3, gD);

  for (int it = 0; it < SEQ / 4; ++it) {
    const int s = 4 * it;
    STEP(s + 0, gA);
    { int sc = (s + 4 < SEQ) ? s + 4 : SEQ - 1; LOADG(sc, gA); }
    STEP(s + 1, gB);
    { int sc = (s + 5 < SEQ) ? s + 5 : SEQ - 1; LOADG(sc, gB); }
    STEP(s + 2, gC);
    { int sc = (s + 6 < SEQ) ? s + 6 : SEQ - 1; LOADG(sc, gC); }
    STEP(s + 3, gD);
    { int sc = (s + 7 < SEQ) ? s + 7 : SEQ - 1; LOADG(sc, gD); }
  }
#undef STEP
#undef LOADG
#undef TT
}

// ---------------------------------------------------------------------------
// Kernel C: CRF log-likelihood. 4 waves/block, 1 wave per batch, 64 blocks.
// Factorized scan: alpha'_k = log(sum_j e^{beta_j} * W[j][k]) + cur_k, with
// W = exp(trans) preloaded per-lane (16 regs, j-split across half-waves),
// e broadcast via 128B LDS slice, drift killed by readfirstlane renorm
// (accumulated into S). No per-step shfl gathers, 1 exp + 1 log per step.
// ---------------------------------------------------------------------------
__global__ __launch_bounds__(256)
void crf_kernel(const float* __restrict__ Lf,
                const float* __restrict__ Lb,
                const float* __restrict__ trans,
                const int* __restrict__ labels,
                float* __restrict__ out) {
  const int wv = threadIdx.x >> 6;
  const int b  = blockIdx.x * 4 + wv;
  const int lane = threadIdx.x & 63;
  const int k  = lane & 31;
  const int jh = lane >> 5;

  __shared__ float tr[TAGS * TAGS];
  __shared__ __align__(16) float e_lds[4][TAGS];

  for (int i = threadIdx.x; i < TAGS * TAGS; i += 256) tr[i] = trans[i];
  __syncthreads();

  float wxp[16];
  #pragma unroll
  for (int i = 0; i < 16; ++i) wxp[i] = __expf(tr[(jh * 16 + i) * TAGS + k]);

  const size_t base0 = (size_t)b * SEQ * TAGS;
  float cur = Lf[base0 + k] + Lb[base0 + k];
  float b00 = __builtin_amdgcn_readfirstlane(__builtin_bit_cast(int, cur))
                  ? 0.f : 0.f;  // placeholder avoided; do it properly below
  // renorm by lane0's value
  float beta0 = __shfl(cur, 0);
  float beta = cur - beta0;
  float S = beta0;

  float nxt = Lf[base0 + TAGS + k] + Lb[base0 + TAGS + k];

  for (int t = 1; t < SEQ; ++t) {
    float e = __expf(beta);
    if (lane < TAGS) e_lds[wv][k] = e;
    asm volatile("s_waitcnt lgkmcnt(0)" ::: "memory");
    const float4* ep = (const float4*)&e_lds[wv][jh * 16];
    float4 e0 = ep[0], e1 = ep[1], e2 = ep[2], e3 = ep[3];
    float d0 = e0.x * wxp[0]  + e0.y * wxp[1]  + e0.z * wxp[2]  + e0.w * wxp[3];
    float d1 = e1.x * wxp[4]  + e1.y * wxp[5]  + e1.z * wxp[6]  + e1.w * wxp[7];
    float d2 = e2.x * wxp[8]  + e2.y * wxp[9]  + e2.z * wxp[10] + e2.w * wxp[11];
    float d3 = e3.x * wxp[12] + e3.y * wxp[13] + e3.z * wxp[14] + e3.w * wxp[15];
    float dot = (d0 + d1) + (d2 + d3);
    dot += __shfl_xor(dot, 32);
    float braw = __logf(dot) + nxt;
    float bz = __shfl(braw, 0);
    beta = braw - bz;
    S += bz;
    if (t + 1 < SEQ) {
      size_t idx = base0 + (size_t)(t + 1) * TAGS + k;
      nxt = Lf[idx] + Lb[idx];
    }
  }

  // log_norm = S + logsumexp(beta)
  float m = beta;
  #pragma unroll
  for (int off = 1; off <= 16; off <<= 1) m = fmaxf(m, __shfl_xor(m, off));
  float ex = (lane < TAGS) ? __expf(beta - m) : 0.0f;
  float s = ex;
  #pragma unroll
  for (int off = 1; off <= 32; off <<= 1) s += __shfl_xor(s, off);

  const int* lab = labels + (size_t)b * SEQ;
  float uacc = 0.f, bacc = 0.f;
  for (int t = lane; t < SEQ; t += 64) {
    int l0 = lab[t];
    size_t idx = base0 + (size_t)t * TAGS + l0;
    uacc += Lf[idx] + Lb[idx];
    if (t + 1 < SEQ) bacc += tr[l0 * TAGS + lab[t + 1]];
  }
  float red = uacc + bacc;
  #pragma unroll
  for (int off = 1; off <= 32; off <<= 1) red += __shfl_xor(red, off);

  if (lane == 0) out[b] = red - (m + __logf(s) + S);
}

// ---------------------------------------------------------------------------
// Kernel D: copy transition matrix to the second output slot.
// ---------------------------------------------------------------------------
__global__ void copy_trans_kernel(const float* __restrict__ trans,
                                  float* __restrict__ out) {
  int i = blockIdx.x * blockDim.x + threadIdx.x;
  if (i < TAGS * TAGS) out[i] = trans[i];
}

extern "C" void kernel_launch(void* const* d_in, const int* in_sizes, int n_in,
                              void* d_out, int out_size, void* d_ws, size_t ws_size,
                              hipStream_t stream) {
  const int*   inputs = (const int*)  d_in[0];
  const int*   labels = (const int*)  d_in[1];
  const float* E      = (const float*)d_in[2];
  const float* Wk_f   = (const float*)d_in[3];
  const float* Wr_f   = (const float*)d_in[4];
  const float* b_f    = (const float*)d_in[5];
  const float* Wk_b   = (const float*)d_in[6];
  const float* Wr_b   = (const float*)d_in[7];
  const float* b_b    = (const float*)d_in[8];
  const float* Wd     = (const float*)d_in[9];
  const float* bd     = (const float*)d_in[10];
  const float* trans  = (const float*)d_in[11];
  float* out = (float*)d_out;

  char* ws = (char*)d_ws;
  const size_t G_ELEMS = (size_t)VOCAB * G4;            // 25,600,512 f16 each dir
  f16* G_f = (f16*)ws;
  f16* G_b = G_f + G_ELEMS;
  float* Lfp = (float*)(ws + 2 * G_ELEMS * sizeof(f16));
  float* Lbp = Lfp + (size_t)BATCH * SEQ * TAGS;

  dim3 ggrid((VOCAB + 63) / 64, 2, 2);
  gtab_mfma_kernel<<<ggrid, 256, 0, stream>>>(E, Wk_f, b_f, Wk_b, b_b, G_f, G_b);

  lstm_mfma_kernel<<<dim3(BATCH / 2, 2), 512, 0, stream>>>(
      inputs, G_f, G_b, Wr_f, Wr_b, Wd, bd, Lfp, Lbp);

  crf_kernel<<<BATCH / 4, 256, 0, stream>>>(Lfp, Lbp, trans, labels, out);

  copy_trans_kernel<<<(TAGS * TAGS + 255) / 256, 256, 0, stream>>>(trans, out + BATCH);
}